// Round 8
// baseline (13221.538 us; speedup 1.0000x reference)
//
#include <hip/hip_runtime.h>
#include <cstdint>
#include <cstddef>

#define DEVFN __device__ __forceinline__

DEVFN float sigmf(float x) { return 1.0f / (1.0f + expf(-x)); }

// =====================================================================
// GEMM v4 (unchanged; verified healthy: VGPR 64, no spill, VALU ~75%).
// C[rowmap(m), n] = act( sum_k A[m,k]*B[n,k] + bias[n] )
// Block 512 thr = 8 waves (4m x 2n), macro-tile 128x128, BK=16.
// RMAP: 0 identity; 1: (m%80)*128+m/80 ; 2: (m&127)*10+(m>>7)
// =====================================================================
template <int ACT, int RMAP>
__global__ __launch_bounds__(512, 4) void gemm_k(
    const float* __restrict__ A, const float* __restrict__ B,
    const float* __restrict__ bias, float* __restrict__ C, int K, int ldc) {
  constexpr int SST = 132;
  __shared__ float As[2][16 * SST];
  __shared__ float Bs[2][16 * SST];
  const int tid = threadIdx.x;
  const int mA = blockIdx.y * 128;
  const int n0 = blockIdx.x * 128;

  const int sm = tid >> 2;  // 0..127 (tile row)
  const int sq = tid & 3;   // k-quad 0..3
  const float* __restrict__ Ap = A + (size_t)(mA + sm) * K + sq * 4;
  const float* __restrict__ Bp = B + (size_t)(n0 + sm) * K + sq * 4;

  const int w = tid >> 6;   // 0..7
  const int lane = tid & 63;
  const int am0 = (w >> 1) * 32 + (lane >> 3) * 4;  // LDS m base (4 rows)
  const int bn0 = (w & 1) * 64 + (lane & 7) * 4;    // LDS n base (8 cols)

  const float4 fz = {0.f, 0.f, 0.f, 0.f};
  float4 c0a = fz, c0b = fz, c1a = fz, c1b = fz, c2a = fz, c2b = fz,
         c3a = fz, c3b = fz;

#define STAGE_WR(AW, BW, ga, gb)          \
  do {                                    \
    const int kq = sq * 4;                \
    (AW)[(kq + 0) * SST + sm] = (ga).x;   \
    (AW)[(kq + 1) * SST + sm] = (ga).y;   \
    (AW)[(kq + 2) * SST + sm] = (ga).z;   \
    (AW)[(kq + 3) * SST + sm] = (ga).w;   \
    (BW)[(kq + 0) * SST + sm] = (gb).x;   \
    (BW)[(kq + 1) * SST + sm] = (gb).y;   \
    (BW)[(kq + 2) * SST + sm] = (gb).z;   \
    (BW)[(kq + 3) * SST + sm] = (gb).w;   \
  } while (0)

#define FMA8(AV, CA, CB)            \
  CA.x = fmaf(AV, b0.x, CA.x);      \
  CA.y = fmaf(AV, b0.y, CA.y);      \
  CA.z = fmaf(AV, b0.z, CA.z);      \
  CA.w = fmaf(AV, b0.w, CA.w);      \
  CB.x = fmaf(AV, b1.x, CB.x);      \
  CB.y = fmaf(AV, b1.y, CB.y);      \
  CB.z = fmaf(AV, b1.z, CB.z);      \
  CB.w = fmaf(AV, b1.w, CB.w);

#define COMPUTE_TILE(Ab, Bb)                                    \
  _Pragma("unroll") for (int k = 0; k < 16; ++k) {              \
    const float4 av = *(const float4*)&(Ab)[k * SST + am0];     \
    const float4 b0 = *(const float4*)&(Bb)[k * SST + bn0];     \
    const float4 b1 = *(const float4*)&(Bb)[k * SST + bn0 + 32];\
    FMA8(av.x, c0a, c0b)                                        \
    FMA8(av.y, c1a, c1b)                                        \
    FMA8(av.z, c2a, c2b)                                        \
    FMA8(av.w, c3a, c3b)                                        \
  }

  {
    const float4 ga = *(const float4*)Ap;
    const float4 gb = *(const float4*)Bp;
    STAGE_WR(As[0], Bs[0], ga, gb);
  }
  __syncthreads();

  const int nt = K >> 4;
  for (int t = 0; t < nt - 1; ++t) {
    const int kc = (t + 1) << 4;
    const float4 ga = *(const float4*)(Ap + kc);
    const float4 gb = *(const float4*)(Bp + kc);
    const float* __restrict__ Ab = As[t & 1];
    const float* __restrict__ Bb = Bs[t & 1];
    COMPUTE_TILE(Ab, Bb)
    STAGE_WR(As[(t & 1) ^ 1], Bs[(t & 1) ^ 1], ga, gb);
    __syncthreads();
  }
  {
    const float* __restrict__ Ab = As[(nt - 1) & 1];
    const float* __restrict__ Bb = Bs[(nt - 1) & 1];
    COMPUTE_TILE(Ab, Bb)
  }
#undef STAGE_WR
#undef FMA8
#undef COMPUTE_TILE

  const float4 bv0 = *(const float4*)&bias[n0 + bn0];
  const float4 bv1 = *(const float4*)&bias[n0 + bn0 + 32];
#define EPI_ROW(IDX, CA, CB)                                         \
  {                                                                  \
    const int m = mA + am0 + (IDX);                                  \
    int cr;                                                          \
    if (RMAP == 0) cr = m;                                           \
    else if (RMAP == 1) cr = (m % 80) * 128 + m / 80;                \
    else cr = (m & 127) * 10 + (m >> 7);                             \
    float* Cp = C + (size_t)cr * ldc + n0 + bn0;                     \
    float4 o0, o1;                                                   \
    float v;                                                         \
    v = CA.x + bv0.x; o0.x = ACT ? fmaxf(v, 0.f) : v;                \
    v = CA.y + bv0.y; o0.y = ACT ? fmaxf(v, 0.f) : v;                \
    v = CA.z + bv0.z; o0.z = ACT ? fmaxf(v, 0.f) : v;                \
    v = CA.w + bv0.w; o0.w = ACT ? fmaxf(v, 0.f) : v;                \
    v = CB.x + bv1.x; o1.x = ACT ? fmaxf(v, 0.f) : v;                \
    v = CB.y + bv1.y; o1.y = ACT ? fmaxf(v, 0.f) : v;                \
    v = CB.z + bv1.z; o1.z = ACT ? fmaxf(v, 0.f) : v;                \
    v = CB.w + bv1.w; o1.w = ACT ? fmaxf(v, 0.f) : v;                \
    *(float4*)&Cp[0] = o0;                                           \
    *(float4*)&Cp[32] = o1;                                          \
  }
  EPI_ROW(0, c0a, c0b)
  EPI_ROW(1, c1a, c1b)
  EPI_ROW(2, c2a, c2b)
  EPI_ROW(3, c3a, c3b)
#undef EPI_ROW
}

// =====================================================================
// GRU sequence kernel v2. Grid (jt 0..7, bt 0..7, d 0..D-1) = 128/64
// blocks, 512 thr. flat_id % 8 == jt -> all readers of a given whh
// j-slice land on ONE XCD: hot set 786KB/XCD -> whh stays L2-resident
// (R7 thrashed: full 6.2MB needed on every XCD, 2.8MB/step L2 miss).
// Block owns j0=jt*64 (64 h-outputs) x b0=bt*16 (16 batch rows), done
// as two 32-j passes of the 12-row/wave gh pipeline.
// h exchange: 8-byte agent-scope atomics (coherence point = MALL,
// bypasses non-coherent per-XCD L2); ordering via 8-block group
// barrier (release fetch_add + acquire spin), groups = (bt,d).
// gi gate values for step i+1 prefetched into regs before the spin.
// LDS: h 16x516 + gh 96x17 + hout 16x68 = 43.9 KB -> 1 block/CU under
// any accounting; coop launch of 128 blocks always fits.
// Unified t0/nsteps/Tfull so the same kernel serves the cooperative
// sequence (t0=0,nsteps=T) and the per-step fallback (nsteps=1).
// =====================================================================
__global__ __launch_bounds__(512, 1) void gru_seq_k(
    const float* h_init, float* hb0, float* hb1, const float* __restrict__ gi,
    int gi_ld, const float* __restrict__ whh, const float* __restrict__ bhh,
    float* __restrict__ y, int y_ld, int t0, int nsteps, int Tfull,
    unsigned* bar) {
  __shared__ float lds_h[16 * 516];
  __shared__ float gh_lds[96 * 17];
  __shared__ float hout[16 * 68];
  const int tid = threadIdx.x;
  const int jt = blockIdx.x;  // 0..7 -> XCD
  const int bt = blockIdx.y;  // 0..7
  const int d = blockIdx.z;
  const int D = gridDim.z;
  const int nb = gridDim.x;  // blocks per barrier group (8)
  const int doff = d * 1536;
  const int j0 = jt * 64;
  const int b0 = bt * 16;
  const int grp = bt * D + d;

  const int w = tid >> 6;
  const int lane = tid & 63;
  const int b_loc = lane & 15;
  const int kh = lane >> 4;
  const int kbase = kh * 128;

  // gate-phase constants: two j per thread (jgA = half0, jgB = half1)
  const int jh2 = tid & 31;
  const int b2 = tid >> 5;  // 0..15
  const int bg = b0 + b2;
  const int jgA = j0 + jh2;
  const int jgB = j0 + 32 + jh2;
  const float bhA_r = bhh[doff + jgA];
  const float bhA_z = bhh[doff + 512 + jgA];
  const float bhA_n = bhh[doff + 1024 + jgA];
  const float bhB_r = bhh[doff + jgB];
  const float bhB_z = bhh[doff + 512 + jgB];
  const float bhB_n = bhh[doff + 1024 + jgB];

  // prefetch first step's gi gate values
  float pgA_r, pgA_z, pgA_n, pgB_r, pgB_z, pgB_n;
  {
    const int t_d = (d == 0) ? t0 : (Tfull - 1 - t0);
    const float* g0 = gi + (size_t)(t_d * 128 + bg) * gi_ld + doff;
    pgA_r = g0[jgA]; pgA_z = g0[512 + jgA]; pgA_n = g0[1024 + jgA];
    pgB_r = g0[jgB]; pgB_z = g0[512 + jgB]; pgB_n = g0[1024 + jgB];
  }

  for (int i = 0; i < nsteps; ++i) {
    const int step = t0 + i;
    const int t_d = (d == 0) ? step : (Tfull - 1 - step);
    const float* hsrc = (step == 0) ? h_init : ((step & 1) ? hb1 : hb0);
    float* hdst = (step & 1) ? hb0 : hb1;

    // ---- stage h tile (16 x 512) via 8B agent loads ----
    if (hsrc) {
      const unsigned long long* hp = (const unsigned long long*)(
          hsrc + ((size_t)(d * 128 + b0)) * 512);
#pragma unroll
      for (int c = 0; c < 8; ++c) {
        const int idx = c * 512 + tid;  // 0..4095
        const int r = idx >> 8, kp = idx & 255;
        const unsigned long long v = __hip_atomic_load(
            &hp[(size_t)r * 256 + kp], __ATOMIC_RELAXED,
            __HIP_MEMORY_SCOPE_AGENT);
        *(unsigned long long*)&lds_h[r * 516 + kp * 2] = v;
      }
    } else {
#pragma unroll
      for (int c = 0; c < 17; ++c) {
        const int idx = c * 512 + tid;
        if (idx < 16 * 516) lds_h[idx] = 0.f;
      }
    }
    __syncthreads();

    float hnA = 0.f, hnB = 0.f;
#pragma unroll
    for (int half = 0; half < 2; ++half) {
      const int jbase = j0 + half * 32;
      // gh for 96 rows (3 gates x 32 j), 12 rows per wave
      const float* wr[12];
      float acc[12];
#pragma unroll
      for (int q = 0; q < 12; ++q) {
        const int rl = w * 12 + q;
        const int g = rl >> 5, jh = rl & 31;
        wr[q] = whh + ((size_t)(doff + g * 512 + jbase + jh)) * 512 + kbase;
        acc[q] = 0.f;
      }
      const float* hrow = &lds_h[b_loc * 516 + kbase];
      for (int k8 = 0; k8 < 128; k8 += 8) {
        const float4 a0 = *(const float4*)&hrow[k8];
        const float4 a1 = *(const float4*)&hrow[k8 + 4];
#pragma unroll
        for (int q = 0; q < 12; ++q) {
          const float* r_ = wr[q] + k8;
          acc[q] += r_[0] * a0.x + r_[1] * a0.y + r_[2] * a0.z +
                    r_[3] * a0.w + r_[4] * a1.x + r_[5] * a1.y +
                    r_[6] * a1.z + r_[7] * a1.w;
        }
      }
#pragma unroll
      for (int q = 0; q < 12; ++q) {
        acc[q] += __shfl_xor(acc[q], 16);
        acc[q] += __shfl_xor(acc[q], 32);
      }
      if (kh == 0) {
#pragma unroll
        for (int q = 0; q < 12; ++q)
          gh_lds[(w * 12 + q) * 17 + b_loc] = acc[q];
      }
      __syncthreads();

      // gate phase for this half: one j per thread
      const float ghr = gh_lds[jh2 * 17 + b2];
      const float ghz = gh_lds[(32 + jh2) * 17 + b2];
      const float ghn = gh_lds[(64 + jh2) * 17 + b2];
      const float g_r = half ? pgB_r : pgA_r;
      const float g_z = half ? pgB_z : pgA_z;
      const float g_n = half ? pgB_n : pgA_n;
      const float bh_r = half ? bhB_r : bhA_r;
      const float bh_z = half ? bhB_z : bhA_z;
      const float bh_n = half ? bhB_n : bhA_n;
      const int jg = half ? jgB : jgA;
      const float r = sigmf(g_r + ghr + bh_r);
      const float z = sigmf(g_z + ghz + bh_z);
      const float n = tanhf(g_n + r * (ghn + bh_n));
      const float hold = lds_h[b2 * 516 + jg];
      const float hnew = (1.f - z) * n + z * hold;
      if (half) hnB = hnew; else hnA = hnew;
      hout[b2 * 68 + half * 32 + jh2] = hnew;
      y[((size_t)(t_d * 128 + bg)) * y_ld + d * 512 + jg] = hnew;  // plain
      __syncthreads();  // gh_lds reuse / hout complete
    }

    // ---- write new h tile (16 x 64) via 8B agent stores ----
    {
      unsigned long long* hq = (unsigned long long*)(
          hdst + ((size_t)(d * 128 + b0)) * 512 + j0);
      const int r = tid >> 5, kp = tid & 31;  // 16 rows x 32 ull
      const unsigned long long v =
          *(const unsigned long long*)&hout[r * 68 + kp * 2];
      __hip_atomic_store(&hq[(size_t)r * 256 + kp], v, __ATOMIC_RELAXED,
                         __HIP_MEMORY_SCOPE_AGENT);
    }

    if (i + 1 < nsteps) {
      // prefetch next step's gi gate values (hidden under the barrier)
      const int tn = (d == 0) ? (step + 1) : (Tfull - 2 - step);
      const float* gn = gi + (size_t)(tn * 128 + bg) * gi_ld + doff;
      pgA_r = gn[jgA]; pgA_z = gn[512 + jgA]; pgA_n = gn[1024 + jgA];
      pgB_r = gn[jgB]; pgB_z = gn[512 + jgB]; pgB_n = gn[1024 + jgB];
      __syncthreads();  // drains vmcnt: h stores + prefetch loads done
      if (tid == 0) {
        unsigned* c = &bar[(unsigned)i * 16 + grp];
        __hip_atomic_fetch_add(c, 1u, __ATOMIC_RELEASE,
                               __HIP_MEMORY_SCOPE_AGENT);
        while (__hip_atomic_load(c, __ATOMIC_ACQUIRE,
                                 __HIP_MEMORY_SCOPE_AGENT) < (unsigned)nb)
          __builtin_amdgcn_s_sleep(1);
      }
      __syncthreads();
    }
  }
}

static void run_gru(const float* h_init, float* hb0, float* hb1,
                    const float* gi, int gi_ld, const float* whh,
                    const float* bhh, float* y, int y_ld, int T, int D,
                    unsigned* bar, hipStream_t stream) {
  int t0 = 0, nsteps = T, Tfull = T;
  void* args[] = {(void*)&h_init, (void*)&hb0,  (void*)&hb1, (void*)&gi,
                  (void*)&gi_ld,  (void*)&whh,  (void*)&bhh, (void*)&y,
                  (void*)&y_ld,   (void*)&t0,   (void*)&nsteps,
                  (void*)&Tfull,  (void*)&bar};
  hipError_t e = hipLaunchCooperativeKernel((void*)gru_seq_k, dim3(8, 8, D),
                                            dim3(512, 1, 1), args, 0, stream);
  if (e != hipSuccess) {
    // deterministic fallback: same kernel, one step per normal launch
    for (int i = 0; i < T; ++i) {
      const float* hs = (i == 0) ? h_init : ((i & 1) ? hb1 : hb0);
      gru_seq_k<<<dim3(8, 8, D), dim3(512, 1, 1), 0, stream>>>(
          hs, hb0, hb1, gi, gi_ld, whh, bhh, y, y_ld, i, 1, T, bar);
    }
  }
}

// =====================================================================
// encode_out[t,b,h] = y1[t,b,h] + y1[t,b,512+h]   (float4 granularity)
// =====================================================================
__global__ void fold_k(const float* __restrict__ y1, float* __restrict__ eo) {
  const size_t i = (size_t)blockIdx.x * 256 + threadIdx.x; // float4 index
  const size_t r = i >> 7;
  const int k4 = (int)(i & 127);
  const float* s = y1 + r * 1024 + k4 * 4;
  const float4 a = *(const float4*)s;
  const float4 c = *(const float4*)(s + 512);
  float4 o;
  o.x = a.x + c.x; o.y = a.y + c.y; o.z = a.z + c.z; o.w = a.w + c.w;
  *(float4*)&eo[r * 512 + k4 * 4] = o;
}

// emb_g[l*128+b, :] = embed[target[b,l], :]
__global__ void gather_k(const float* __restrict__ embed,
                         const int* __restrict__ target,
                         float* __restrict__ out) {
  const int rowid = blockIdx.x; // l*128+b
  const int l = rowid >> 7, b = rowid & 127;
  const int wd = target[b * 10 + l];
  const float4* src = (const float4*)(embed + (size_t)wd * 512);
  float4* dst = (float4*)(out + (size_t)rowid * 512);
  dst[threadIdx.x] = src[threadIdx.x];
}

// =====================================================================
// Attention per (l,b): scores over T=80, softmax, ctx; writes Z row
// [ctx(512) | hn(512)].  enc: (T,B,512) rows t*128+b. hn: (L*B,512).
// =====================================================================
__global__ __launch_bounds__(256) void attn_k(const float* __restrict__ enc,
                                              const float* __restrict__ hn_all,
                                              float* __restrict__ Z) {
  __shared__ float hs[512];
  __shared__ float sc[80];
  __shared__ float att[80];
  const int l = blockIdx.x >> 7;
  const int b = blockIdx.x & 127;
  const int tid = threadIdx.x;
  const size_t hrow = (size_t)(l * 128 + b) * 512;
  if (tid < 128)
    *(float4*)&hs[tid * 4] = *(const float4*)&hn_all[hrow + tid * 4];
  __syncthreads();
  const int w = tid >> 6, lane = tid & 63;
  for (int t = w; t < 80; t += 4) {
    const float* e = enc + ((size_t)(t * 128 + b)) * 512 + lane * 8;
    const float4 e0 = *(const float4*)e;
    const float4 e1 = *(const float4*)(e + 4);
    const float* h8 = &hs[lane * 8];
    float p = e0.x * h8[0] + e0.y * h8[1] + e0.z * h8[2] + e0.w * h8[3] +
              e1.x * h8[4] + e1.y * h8[5] + e1.z * h8[6] + e1.w * h8[7];
#pragma unroll
    for (int off = 1; off < 64; off <<= 1) p += __shfl_xor(p, off);
    if (lane == 0) sc[t] = p;
  }
  __syncthreads();
  if (w == 0) {
    const float v0 = sc[lane];
    const float v1 = (lane < 16) ? sc[64 + lane] : -3.4e38f;
    float m = fmaxf(v0, v1);
#pragma unroll
    for (int off = 1; off < 64; off <<= 1) m = fmaxf(m, __shfl_xor(m, off));
    const float e0 = expf(v0 - m);
    const float e1 = (lane < 16) ? expf(v1 - m) : 0.f;
    float s = e0 + e1;
#pragma unroll
    for (int off = 1; off < 64; off <<= 1) s += __shfl_xor(s, off);
    att[lane] = e0 / s;
    if (lane < 16) att[64 + lane] = e1 / s;
  }
  __syncthreads();
  float c0 = 0.f, c1 = 0.f;
  for (int t = 0; t < 80; ++t) {
    const float* e = enc + ((size_t)(t * 128 + b)) * 512;
    const float a = att[t];
    c0 += a * e[tid];
    c1 += a * e[tid + 256];
  }
  const size_t zr = (size_t)(l * 128 + b) * 1024;
  Z[zr + tid] = c0;
  Z[zr + 256 + tid] = c1;
  Z[zr + 512 + tid] = hs[tid];
  Z[zr + 768 + tid] = hs[256 + tid];
}

// =====================================================================
// Per row (b*10+l) of d_out: argmax (first-index ties) + logsumexp,
// in-place log_softmax, write pre_sent[l*128+b] as float.
// =====================================================================
__global__ __launch_bounds__(256) void lsm_k(float* __restrict__ out) {
  const int row = blockIdx.x; // b*10 + l
  float* p = out + (size_t)row * 32000;
  const int tid = threadIdx.x;
  float bv = -3.4e38f;
  int bi = 0;
  for (int c = 0; c < 125; ++c) {
    const int idx = c * 256 + tid;
    const float v = p[idx];
    if (v > bv || (v == bv && idx < bi)) { bv = v; bi = idx; }
  }
#pragma unroll
  for (int off = 1; off < 64; off <<= 1) {
    const float ov = __shfl_xor(bv, off);
    const int oi = __shfl_xor(bi, off);
    if (ov > bv || (ov == bv && oi < bi)) { bv = ov; bi = oi; }
  }
  __shared__ float wv[4];
  __shared__ int wi[4];
  __shared__ float wsm[4];
  const int w = tid >> 6, lane = tid & 63;
  if (lane == 0) { wv[w] = bv; wi[w] = bi; }
  __syncthreads();
  float m = wv[0];
  int mi = wi[0];
#pragma unroll
  for (int q = 1; q < 4; ++q) {
    if (wv[q] > m || (wv[q] == m && wi[q] < mi)) { m = wv[q]; mi = wi[q]; }
  }
  float s = 0.f;
  for (int c = 0; c < 125; ++c) s += expf(p[c * 256 + tid] - m);
#pragma unroll
  for (int off = 1; off < 64; off <<= 1) s += __shfl_xor(s, off);
  if (lane == 0) wsm[w] = s;
  __syncthreads();
  const float lse = m + logf(wsm[0] + wsm[1] + wsm[2] + wsm[3]);
  for (int c = 0; c < 125; ++c) {
    const int idx = c * 256 + tid;
    p[idx] = p[idx] - lse;
  }
  if (tid == 0) out[40960000 + (row % 10) * 128 + (row / 10)] = (float)mi;
}

// =====================================================================
extern "C" void kernel_launch(void* const* d_in, const int* in_sizes, int n_in,
                              void* d_out, int out_size, void* d_ws,
                              size_t ws_size, hipStream_t stream) {
  (void)in_sizes; (void)n_in; (void)out_size; (void)ws_size;
  const float* data = (const float*)d_in[0];
  const int* target = (const int*)d_in[1];
  const float* enc_lin_w = (const float*)d_in[2];
  const float* enc_lin_b = (const float*)d_in[3];
  const float* enc_wih0 = (const float*)d_in[4];
  const float* enc_whh0 = (const float*)d_in[5];
  const float* enc_bih0 = (const float*)d_in[6];
  const float* enc_bhh0 = (const float*)d_in[7];
  const float* enc_wih1 = (const float*)d_in[8];
  const float* enc_whh1 = (const float*)d_in[9];
  const float* enc_bih1 = (const float*)d_in[10];
  const float* enc_bhh1 = (const float*)d_in[11];
  const float* dec_wih = (const float*)d_in[12];
  const float* dec_whh = (const float*)d_in[13];
  const float* dec_bih = (const float*)d_in[14];
  const float* dec_bhh = (const float*)d_in[15];
  const float* out_w = (const float*)d_in[16];
  const float* out_b = (const float*)d_in[17];
  const float* embed = (const float*)d_in[18];
  float* outp = (float*)d_out;

  float* ws = (float*)d_ws;
  size_t off = 0;
  float* buf_gi = ws + off;  off += 31457280;  // (10240, 3072) gi0 then gi1
  float* buf_x = ws + off;   off += 5242880;   // x (T,B,512); later enc_out
  float* buf_y0 = ws + off;  off += 10485760;  // (T,B,1024)
  float* buf_y1 = ws + off;  off += 10485760;  // (T,B,1024)
  float* h_pp0 = ws + off;   off += 131072;    // (2,128,512)
  float* h_pp1 = ws + off;   off += 131072;
  float* dec_pp0 = ws + off; off += 65536;     // (128,512)
  float* dec_pp1 = ws + off; off += 65536;
  float* emb_g = ws + off;   off += 655360;    // (1280,512)
  float* gi_dec = ws + off;  off += 1966080;   // (1280,1536)
  float* hn_all = ws + off;  off += 655360;    // (1280,512)
  float* Zb = ws + off;      off += 1310720;   // (1280,1024)
  unsigned* bar = (unsigned*)(ws + off); off += 4096;  // barrier counters

  // zero barrier counters (captured -> re-zeroed on every graph replay)
  hipMemsetAsync(bar, 0, 4096 * sizeof(unsigned), stream);

  // ---- Encoder linear + ReLU: x(t*128+b, 512) ----
  gemm_k<1, 1><<<dim3(4, 80), 512, 0, stream>>>(data, enc_lin_w, enc_lin_b,
                                                buf_x, 4096, 512);
  // ---- gi0 = x @ wih0^T (+bih0), both dirs stacked in 3072 cols ----
  gemm_k<0, 0><<<dim3(24, 80), 512, 0, stream>>>(buf_x, enc_wih0, enc_bih0,
                                                 buf_gi, 512, 3072);
  // ---- layer-0 recurrence (h_init = nullptr -> zeros) ----
  run_gru(nullptr, h_pp0, h_pp1, buf_gi, 3072, enc_whh0, enc_bhh0, buf_y0,
          1024, 80, 2, bar, stream);
  // ---- gi1 = y0 @ wih1^T (+bih1) ----
  gemm_k<0, 0><<<dim3(24, 80), 512, 0, stream>>>(buf_y0, enc_wih1, enc_bih1,
                                                 buf_gi, 1024, 3072);
  // ---- layer-1 recurrence ----
  run_gru(nullptr, h_pp0, h_pp1, buf_gi, 3072, enc_whh1, enc_bhh1, buf_y1,
          1024, 80, 2, bar + 1280, stream);
  // final hidden (both dirs) in h_pp1 if T odd else h_pp0; T=80 even ->
  // last write (step 79, odd) went to hb0 = h_pp0. decode_hid = d=1 slice.
  // ---- encode_out = y1[:, :512] + y1[:, 512:]  (into buf_x) ----
  fold_k<<<5120, 256, 0, stream>>>(buf_y1, buf_x);
  // ---- decoder input projections ----
  gather_k<<<1280, 128, 0, stream>>>(embed, target, emb_g);
  gemm_k<0, 0><<<dim3(12, 10), 512, 0, stream>>>(emb_g, dec_wih, dec_bih,
                                                 gi_dec, 512, 1536);
  // ---- decoder hidden chain (teacher forcing) ----
  const float* dec_h0 = h_pp0 + 128 * 512;  // layer-1 backward final hidden
  run_gru(dec_h0, dec_pp0, dec_pp1, gi_dec, 1536, dec_whh, dec_bhh, hn_all,
          512, 10, 1, bar + 2560, stream);
  // ---- attention + Z = [ctx | hn] ----
  attn_k<<<1280, 256, 0, stream>>>(buf_x, hn_all, Zb);
  // ---- logits GEMM straight into d_out rows (b*10+l) ----
  gemm_k<0, 2><<<dim3(250, 10), 512, 0, stream>>>(Zb, out_w, out_b, outp, 1024,
                                                  32000);
  // ---- log_softmax in place + argmax -> pre_sent ----
  lsm_k<<<1280, 256, 0, stream>>>(outp);
}

// Round 9
// 7653.863 us; speedup vs baseline: 1.7274x; 1.7274x over previous
//
#include <hip/hip_runtime.h>
#include <cstdint>
#include <cstddef>

#define DEVFN __device__ __forceinline__

DEVFN float sigmf(float x) { return 1.0f / (1.0f + expf(-x)); }

// =====================================================================
// GEMM v4 (unchanged; verified healthy: VGPR 64, no spill, VALU ~75%).
// C[rowmap(m), n] = act( sum_k A[m,k]*B[n,k] + bias[n] )
// Block 512 thr = 8 waves (4m x 2n), macro-tile 128x128, BK=16.
// RMAP: 0 identity; 1: (m%80)*128+m/80 ; 2: (m&127)*10+(m>>7)
// =====================================================================
template <int ACT, int RMAP>
__global__ __launch_bounds__(512, 4) void gemm_k(
    const float* __restrict__ A, const float* __restrict__ B,
    const float* __restrict__ bias, float* __restrict__ C, int K, int ldc) {
  constexpr int SST = 132;
  __shared__ float As[2][16 * SST];
  __shared__ float Bs[2][16 * SST];
  const int tid = threadIdx.x;
  const int mA = blockIdx.y * 128;
  const int n0 = blockIdx.x * 128;

  const int sm = tid >> 2;  // 0..127 (tile row)
  const int sq = tid & 3;   // k-quad 0..3
  const float* __restrict__ Ap = A + (size_t)(mA + sm) * K + sq * 4;
  const float* __restrict__ Bp = B + (size_t)(n0 + sm) * K + sq * 4;

  const int w = tid >> 6;   // 0..7
  const int lane = tid & 63;
  const int am0 = (w >> 1) * 32 + (lane >> 3) * 4;  // LDS m base (4 rows)
  const int bn0 = (w & 1) * 64 + (lane & 7) * 4;    // LDS n base (8 cols)

  const float4 fz = {0.f, 0.f, 0.f, 0.f};
  float4 c0a = fz, c0b = fz, c1a = fz, c1b = fz, c2a = fz, c2b = fz,
         c3a = fz, c3b = fz;

#define STAGE_WR(AW, BW, ga, gb)          \
  do {                                    \
    const int kq = sq * 4;                \
    (AW)[(kq + 0) * SST + sm] = (ga).x;   \
    (AW)[(kq + 1) * SST + sm] = (ga).y;   \
    (AW)[(kq + 2) * SST + sm] = (ga).z;   \
    (AW)[(kq + 3) * SST + sm] = (ga).w;   \
    (BW)[(kq + 0) * SST + sm] = (gb).x;   \
    (BW)[(kq + 1) * SST + sm] = (gb).y;   \
    (BW)[(kq + 2) * SST + sm] = (gb).z;   \
    (BW)[(kq + 3) * SST + sm] = (gb).w;   \
  } while (0)

#define FMA8(AV, CA, CB)            \
  CA.x = fmaf(AV, b0.x, CA.x);      \
  CA.y = fmaf(AV, b0.y, CA.y);      \
  CA.z = fmaf(AV, b0.z, CA.z);      \
  CA.w = fmaf(AV, b0.w, CA.w);      \
  CB.x = fmaf(AV, b1.x, CB.x);      \
  CB.y = fmaf(AV, b1.y, CB.y);      \
  CB.z = fmaf(AV, b1.z, CB.z);      \
  CB.w = fmaf(AV, b1.w, CB.w);

#define COMPUTE_TILE(Ab, Bb)                                    \
  _Pragma("unroll") for (int k = 0; k < 16; ++k) {              \
    const float4 av = *(const float4*)&(Ab)[k * SST + am0];     \
    const float4 b0 = *(const float4*)&(Bb)[k * SST + bn0];     \
    const float4 b1 = *(const float4*)&(Bb)[k * SST + bn0 + 32];\
    FMA8(av.x, c0a, c0b)                                        \
    FMA8(av.y, c1a, c1b)                                        \
    FMA8(av.z, c2a, c2b)                                        \
    FMA8(av.w, c3a, c3b)                                        \
  }

  {
    const float4 ga = *(const float4*)Ap;
    const float4 gb = *(const float4*)Bp;
    STAGE_WR(As[0], Bs[0], ga, gb);
  }
  __syncthreads();

  const int nt = K >> 4;
  for (int t = 0; t < nt - 1; ++t) {
    const int kc = (t + 1) << 4;
    const float4 ga = *(const float4*)(Ap + kc);
    const float4 gb = *(const float4*)(Bp + kc);
    const float* __restrict__ Ab = As[t & 1];
    const float* __restrict__ Bb = Bs[t & 1];
    COMPUTE_TILE(Ab, Bb)
    STAGE_WR(As[(t & 1) ^ 1], Bs[(t & 1) ^ 1], ga, gb);
    __syncthreads();
  }
  {
    const float* __restrict__ Ab = As[(nt - 1) & 1];
    const float* __restrict__ Bb = Bs[(nt - 1) & 1];
    COMPUTE_TILE(Ab, Bb)
  }
#undef STAGE_WR
#undef FMA8
#undef COMPUTE_TILE

  const float4 bv0 = *(const float4*)&bias[n0 + bn0];
  const float4 bv1 = *(const float4*)&bias[n0 + bn0 + 32];
#define EPI_ROW(IDX, CA, CB)                                         \
  {                                                                  \
    const int m = mA + am0 + (IDX);                                  \
    int cr;                                                          \
    if (RMAP == 0) cr = m;                                           \
    else if (RMAP == 1) cr = (m % 80) * 128 + m / 80;                \
    else cr = (m & 127) * 10 + (m >> 7);                             \
    float* Cp = C + (size_t)cr * ldc + n0 + bn0;                     \
    float4 o0, o1;                                                   \
    float v;                                                         \
    v = CA.x + bv0.x; o0.x = ACT ? fmaxf(v, 0.f) : v;                \
    v = CA.y + bv0.y; o0.y = ACT ? fmaxf(v, 0.f) : v;                \
    v = CA.z + bv0.z; o0.z = ACT ? fmaxf(v, 0.f) : v;                \
    v = CA.w + bv0.w; o0.w = ACT ? fmaxf(v, 0.f) : v;                \
    v = CB.x + bv1.x; o1.x = ACT ? fmaxf(v, 0.f) : v;                \
    v = CB.y + bv1.y; o1.y = ACT ? fmaxf(v, 0.f) : v;                \
    v = CB.z + bv1.z; o1.z = ACT ? fmaxf(v, 0.f) : v;                \
    v = CB.w + bv1.w; o1.w = ACT ? fmaxf(v, 0.f) : v;                \
    *(float4*)&Cp[0] = o0;                                           \
    *(float4*)&Cp[32] = o1;                                          \
  }
  EPI_ROW(0, c0a, c0b)
  EPI_ROW(1, c1a, c1b)
  EPI_ROW(2, c2a, c2b)
  EPI_ROW(3, c3a, c3b)
#undef EPI_ROW
}

// =====================================================================
// GRU step v3 (per-step launch, graph-replayed; NO coop/barriers/atomics
// -- R4's 170-launch pattern was the fastest verified structure; R7/R8
// persistent barriers cost 40-60us/step vs ~27us/step launch envelope).
// Changes vs R4 kernel: 16 batch rows/block -> LDS 34.7KB -> 4 blk/CU
// (16 waves/CU, 2x TLP for latency hiding); gi gate + bhh values loaded
// into registers at kernel ENTRY (tail shortening).
// Grid (jt 0..63, bt 0..7, d), 256 thr. Block = 8 j x 16 b.
// gh rows 24 (3 gates x 8 j), 6 per wave; lane: b_loc=lane&15,
// kh=lane>>4 (4 x 128-k segments), shfl_xor(16,32) reduction.
// =====================================================================
__global__ __launch_bounds__(256, 4) void gru_step_k(
    const float* __restrict__ h_prev, float* __restrict__ h_next,
    const float* __restrict__ gi, int gi_ld, const float* __restrict__ whh,
    const float* __restrict__ bhh, float* __restrict__ y, int y_ld, int i,
    int T) {
  __shared__ float lds_h[16 * 516];
  __shared__ float gh_lds[24 * 17];
  const int tid = threadIdx.x;
  const int jt = blockIdx.x;  // 0..63 (8 j each)
  const int bt = blockIdx.y;  // 0..7  (16 b each)
  const int d = blockIdx.z;
  const int t_d = (d == 0) ? i : (T - 1 - i);
  const int doff = d * 1536;
  const int j0 = jt * 8;
  const int b0 = bt * 16;

  // ---- early tail loads: gi gates + bhh for this thread's output ----
  const int jh2 = tid & 7;
  const int b2g = tid >> 3;  // 0..31; only <16 used in gate phase
  float g_r = 0.f, g_z = 0.f, g_n = 0.f, bh_r = 0.f, bh_z = 0.f, bh_n = 0.f;
  if (b2g < 16) {
    const float* gir =
        gi + (size_t)(t_d * 128 + b0 + b2g) * gi_ld + doff + j0 + jh2;
    g_r = gir[0];
    g_z = gir[512];
    g_n = gir[1024];
    bh_r = bhh[doff + j0 + jh2];
    bh_z = bhh[doff + 512 + j0 + jh2];
    bh_n = bhh[doff + 1024 + j0 + jh2];
  }

  // ---- stage h tile (16 x 512) into LDS, stride 516 ----
  {
    const float* hp = h_prev + ((size_t)(d * 128 + b0)) * 512;
#pragma unroll
    for (int c = 0; c < 8; ++c) {
      const int i4 = c * 256 + tid;  // float4 index 0..2047
      const int r = i4 >> 7, k4 = i4 & 127;
      *(float4*)&lds_h[r * 516 + k4 * 4] =
          *(const float4*)&hp[(size_t)r * 512 + k4 * 4];
    }
  }
  __syncthreads();

  const int w = tid >> 6;
  const int lane = tid & 63;
  const int b_loc = lane & 15;
  const int kh = lane >> 4;
  const int kbase = kh * 128;

  const float* wr[6];
#pragma unroll
  for (int q = 0; q < 6; ++q) {
    const int rl = w * 6 + q;
    const int g = rl >> 3, jh = rl & 7;
    wr[q] = whh + ((size_t)(doff + g * 512 + j0 + jh)) * 512 + kbase;
  }
  float acc[6] = {0.f, 0.f, 0.f, 0.f, 0.f, 0.f};
  const float* hrow = &lds_h[b_loc * 516 + kbase];
  for (int k8 = 0; k8 < 128; k8 += 8) {
    const float4 a0 = *(const float4*)&hrow[k8];
    const float4 a1 = *(const float4*)&hrow[k8 + 4];
#pragma unroll
    for (int q = 0; q < 6; ++q) {
      const float* r_ = wr[q] + k8;
      acc[q] += r_[0] * a0.x + r_[1] * a0.y + r_[2] * a0.z + r_[3] * a0.w +
                r_[4] * a1.x + r_[5] * a1.y + r_[6] * a1.z + r_[7] * a1.w;
    }
  }
#pragma unroll
  for (int q = 0; q < 6; ++q) {
    acc[q] += __shfl_xor(acc[q], 16);
    acc[q] += __shfl_xor(acc[q], 32);
  }
  if (kh == 0) {
#pragma unroll
    for (int q = 0; q < 6; ++q) gh_lds[(w * 6 + q) * 17 + b_loc] = acc[q];
  }
  __syncthreads();

  // ---- gate phase: first 128 threads, one (j,b) each ----
  if (b2g < 16) {
    const float ghr = gh_lds[jh2 * 17 + b2g];
    const float ghz = gh_lds[(8 + jh2) * 17 + b2g];
    const float ghn = gh_lds[(16 + jh2) * 17 + b2g];
    const int jg = j0 + jh2;
    const int bg = b0 + b2g;
    const float r = sigmf(g_r + ghr + bh_r);
    const float z = sigmf(g_z + ghz + bh_z);
    const float n = tanhf(g_n + r * (ghn + bh_n));
    const float hold = lds_h[b2g * 516 + jg];
    const float hnew = (1.f - z) * n + z * hold;
    h_next[((size_t)(d * 128 + bg)) * 512 + jg] = hnew;
    y[((size_t)(t_d * 128 + bg)) * y_ld + d * 512 + jg] = hnew;
  }
}

// =====================================================================
// encode_out[t,b,h] = y1[t,b,h] + y1[t,b,512+h]   (float4 granularity)
// =====================================================================
__global__ void fold_k(const float* __restrict__ y1, float* __restrict__ eo) {
  const size_t i = (size_t)blockIdx.x * 256 + threadIdx.x; // float4 index
  const size_t r = i >> 7;
  const int k4 = (int)(i & 127);
  const float* s = y1 + r * 1024 + k4 * 4;
  const float4 a = *(const float4*)s;
  const float4 c = *(const float4*)(s + 512);
  float4 o;
  o.x = a.x + c.x; o.y = a.y + c.y; o.z = a.z + c.z; o.w = a.w + c.w;
  *(float4*)&eo[r * 512 + k4 * 4] = o;
}

// emb_g[l*128+b, :] = embed[target[b,l], :]
__global__ void gather_k(const float* __restrict__ embed,
                         const int* __restrict__ target,
                         float* __restrict__ out) {
  const int rowid = blockIdx.x; // l*128+b
  const int l = rowid >> 7, b = rowid & 127;
  const int wd = target[b * 10 + l];
  const float4* src = (const float4*)(embed + (size_t)wd * 512);
  float4* dst = (float4*)(out + (size_t)rowid * 512);
  dst[threadIdx.x] = src[threadIdx.x];
}

// =====================================================================
// Attention per (l,b): scores over T=80, softmax, ctx; writes Z row
// [ctx(512) | hn(512)].  enc: (T,B,512) rows t*128+b. hn: (L*B,512).
// =====================================================================
__global__ __launch_bounds__(256) void attn_k(const float* __restrict__ enc,
                                              const float* __restrict__ hn_all,
                                              float* __restrict__ Z) {
  __shared__ float hs[512];
  __shared__ float sc[80];
  __shared__ float att[80];
  const int l = blockIdx.x >> 7;
  const int b = blockIdx.x & 127;
  const int tid = threadIdx.x;
  const size_t hrow = (size_t)(l * 128 + b) * 512;
  if (tid < 128)
    *(float4*)&hs[tid * 4] = *(const float4*)&hn_all[hrow + tid * 4];
  __syncthreads();
  const int w = tid >> 6, lane = tid & 63;
  for (int t = w; t < 80; t += 4) {
    const float* e = enc + ((size_t)(t * 128 + b)) * 512 + lane * 8;
    const float4 e0 = *(const float4*)e;
    const float4 e1 = *(const float4*)(e + 4);
    const float* h8 = &hs[lane * 8];
    float p = e0.x * h8[0] + e0.y * h8[1] + e0.z * h8[2] + e0.w * h8[3] +
              e1.x * h8[4] + e1.y * h8[5] + e1.z * h8[6] + e1.w * h8[7];
#pragma unroll
    for (int off = 1; off < 64; off <<= 1) p += __shfl_xor(p, off);
    if (lane == 0) sc[t] = p;
  }
  __syncthreads();
  if (w == 0) {
    const float v0 = sc[lane];
    const float v1 = (lane < 16) ? sc[64 + lane] : -3.4e38f;
    float m = fmaxf(v0, v1);
#pragma unroll
    for (int off = 1; off < 64; off <<= 1) m = fmaxf(m, __shfl_xor(m, off));
    const float e0 = expf(v0 - m);
    const float e1 = (lane < 16) ? expf(v1 - m) : 0.f;
    float s = e0 + e1;
#pragma unroll
    for (int off = 1; off < 64; off <<= 1) s += __shfl_xor(s, off);
    att[lane] = e0 / s;
    if (lane < 16) att[64 + lane] = e1 / s;
  }
  __syncthreads();
  float c0 = 0.f, c1 = 0.f;
  for (int t = 0; t < 80; ++t) {
    const float* e = enc + ((size_t)(t * 128 + b)) * 512;
    const float a = att[t];
    c0 += a * e[tid];
    c1 += a * e[tid + 256];
  }
  const size_t zr = (size_t)(l * 128 + b) * 1024;
  Z[zr + tid] = c0;
  Z[zr + 256 + tid] = c1;
  Z[zr + 512 + tid] = hs[tid];
  Z[zr + 768 + tid] = hs[256 + tid];
}

// =====================================================================
// Per row (b*10+l) of d_out: argmax (first-index ties) + logsumexp,
// in-place log_softmax, write pre_sent[l*128+b] as float.
// =====================================================================
__global__ __launch_bounds__(256) void lsm_k(float* __restrict__ out) {
  const int row = blockIdx.x; // b*10 + l
  float* p = out + (size_t)row * 32000;
  const int tid = threadIdx.x;
  float bv = -3.4e38f;
  int bi = 0;
  for (int c = 0; c < 125; ++c) {
    const int idx = c * 256 + tid;
    const float v = p[idx];
    if (v > bv || (v == bv && idx < bi)) { bv = v; bi = idx; }
  }
#pragma unroll
  for (int off = 1; off < 64; off <<= 1) {
    const float ov = __shfl_xor(bv, off);
    const int oi = __shfl_xor(bi, off);
    if (ov > bv || (ov == bv && oi < bi)) { bv = ov; bi = oi; }
  }
  __shared__ float wv[4];
  __shared__ int wi[4];
  __shared__ float wsm[4];
  const int w = tid >> 6, lane = tid & 63;
  if (lane == 0) { wv[w] = bv; wi[w] = bi; }
  __syncthreads();
  float m = wv[0];
  int mi = wi[0];
#pragma unroll
  for (int q = 1; q < 4; ++q) {
    if (wv[q] > m || (wv[q] == m && wi[q] < mi)) { m = wv[q]; mi = wi[q]; }
  }
  float s = 0.f;
  for (int c = 0; c < 125; ++c) s += expf(p[c * 256 + tid] - m);
#pragma unroll
  for (int off = 1; off < 64; off <<= 1) s += __shfl_xor(s, off);
  if (lane == 0) wsm[w] = s;
  __syncthreads();
  const float lse = m + logf(wsm[0] + wsm[1] + wsm[2] + wsm[3]);
  for (int c = 0; c < 125; ++c) {
    const int idx = c * 256 + tid;
    p[idx] = p[idx] - lse;
  }
  if (tid == 0) out[40960000 + (row % 10) * 128 + (row / 10)] = (float)mi;
}

// =====================================================================
extern "C" void kernel_launch(void* const* d_in, const int* in_sizes, int n_in,
                              void* d_out, int out_size, void* d_ws,
                              size_t ws_size, hipStream_t stream) {
  (void)in_sizes; (void)n_in; (void)out_size; (void)ws_size;
  const float* data = (const float*)d_in[0];
  const int* target = (const int*)d_in[1];
  const float* enc_lin_w = (const float*)d_in[2];
  const float* enc_lin_b = (const float*)d_in[3];
  const float* enc_wih0 = (const float*)d_in[4];
  const float* enc_whh0 = (const float*)d_in[5];
  const float* enc_bih0 = (const float*)d_in[6];
  const float* enc_bhh0 = (const float*)d_in[7];
  const float* enc_wih1 = (const float*)d_in[8];
  const float* enc_whh1 = (const float*)d_in[9];
  const float* enc_bih1 = (const float*)d_in[10];
  const float* enc_bhh1 = (const float*)d_in[11];
  const float* dec_wih = (const float*)d_in[12];
  const float* dec_whh = (const float*)d_in[13];
  const float* dec_bih = (const float*)d_in[14];
  const float* dec_bhh = (const float*)d_in[15];
  const float* out_w = (const float*)d_in[16];
  const float* out_b = (const float*)d_in[17];
  const float* embed = (const float*)d_in[18];
  float* outp = (float*)d_out;

  float* ws = (float*)d_ws;
  size_t off = 0;
  float* buf_gi = ws + off;  off += 31457280;  // (10240, 3072) gi0 then gi1
  float* buf_x = ws + off;   off += 5242880;   // x (T,B,512); later enc_out
  float* buf_y0 = ws + off;  off += 10485760;  // (T,B,1024)
  float* buf_y1 = ws + off;  off += 10485760;  // (T,B,1024)
  float* h_pp0 = ws + off;   off += 131072;    // (2,128,512)
  float* h_pp1 = ws + off;   off += 131072;
  float* dec_pp0 = ws + off; off += 65536;     // (128,512)
  float* dec_pp1 = ws + off; off += 65536;
  float* emb_g = ws + off;   off += 655360;    // (1280,512)
  float* gi_dec = ws + off;  off += 1966080;   // (1280,1536)
  float* hn_all = ws + off;  off += 655360;    // (1280,512)
  float* Zb = ws + off;      off += 1310720;   // (1280,1024)

  // ---- Encoder linear + ReLU: x(t*128+b, 512) ----
  gemm_k<1, 1><<<dim3(4, 80), 512, 0, stream>>>(data, enc_lin_w, enc_lin_b,
                                                buf_x, 4096, 512);
  // ---- gi0 = x @ wih0^T (+bih0), both dirs stacked in 3072 cols ----
  gemm_k<0, 0><<<dim3(24, 80), 512, 0, stream>>>(buf_x, enc_wih0, enc_bih0,
                                                 buf_gi, 512, 3072);
  // ---- layer-0 recurrence ----
  hipMemsetAsync(h_pp0, 0, 2 * 128 * 512 * sizeof(float), stream);
  for (int i = 0; i < 80; ++i) {
    float* hin = (i & 1) ? h_pp1 : h_pp0;
    float* hout = (i & 1) ? h_pp0 : h_pp1;
    gru_step_k<<<dim3(64, 8, 2), 256, 0, stream>>>(
        hin, hout, buf_gi, 3072, enc_whh0, enc_bhh0, buf_y0, 1024, i, 80);
  }
  // ---- gi1 = y0 @ wih1^T (+bih1) ----
  gemm_k<0, 0><<<dim3(24, 80), 512, 0, stream>>>(buf_y0, enc_wih1, enc_bih1,
                                                 buf_gi, 1024, 3072);
  // ---- layer-1 recurrence ----
  hipMemsetAsync(h_pp0, 0, 2 * 128 * 512 * sizeof(float), stream);
  for (int i = 0; i < 80; ++i) {
    float* hin = (i & 1) ? h_pp1 : h_pp0;
    float* hout = (i & 1) ? h_pp0 : h_pp1;
    gru_step_k<<<dim3(64, 8, 2), 256, 0, stream>>>(
        hin, hout, buf_gi, 3072, enc_whh1, enc_bhh1, buf_y1, 1024, i, 80);
  }
  // T=80 even -> final hidden in h_pp0; decode_hid = d=1 slice.
  // ---- encode_out = y1[:, :512] + y1[:, 512:]  (into buf_x) ----
  fold_k<<<5120, 256, 0, stream>>>(buf_y1, buf_x);
  // ---- decoder input projections ----
  gather_k<<<1280, 128, 0, stream>>>(embed, target, emb_g);
  gemm_k<0, 0><<<dim3(12, 10), 512, 0, stream>>>(emb_g, dec_wih, dec_bih,
                                                 gi_dec, 512, 1536);
  // ---- decoder hidden chain (teacher forcing) ----
  for (int l = 0; l < 10; ++l) {
    float* hin = (l == 0) ? (h_pp0 + 128 * 512) : ((l & 1) ? dec_pp1 : dec_pp0);
    float* hout = (l & 1) ? dec_pp0 : dec_pp1;
    gru_step_k<<<dim3(64, 8, 1), 256, 0, stream>>>(
        hin, hout, gi_dec, 1536, dec_whh, dec_bhh, hn_all, 512, l, 10);
  }
  // ---- attention + Z = [ctx | hn] ----
  attn_k<<<1280, 256, 0, stream>>>(buf_x, hn_all, Zb);
  // ---- logits GEMM straight into d_out rows (b*10+l) ----
  gemm_k<0, 2><<<dim3(250, 10), 512, 0, stream>>>(Zb, out_w, out_b, outp, 1024,
                                                  32000);
  // ---- log_softmax in place + argmax -> pre_sent ----
  lsm_k<<<1280, 256, 0, stream>>>(outp);
}